// Round 16
// baseline (34.413 us; speedup 1.0000x reference)
//
#include <hip/hip_runtime.h>

#define RS 7
#define SR 2
#define PD 10
#define CH (PD * RS * RS)   // 490
#define SCALE (1.0f / 16.0f)
#define HH 100
#define WW 100
#define NPLANE (HH * WW)    // 10000
#define SLOTS 2560          // 16B slots per buffer (data 2500 + pad)
#define BUFF (SLOTS * 4)    // 10240 floats = 40.96 KB
#define TPB 1024
#define NBLK 256
#define NB 4
#define MAXN 4096
#define RSL 2               // register param slots per thread (covers cnt <= 2048)

// async global->LDS, 16B per lane; LDS dest is WAVE-UNIFORM base (+lane*16 by HW)
__device__ __forceinline__ void gll16(const void* g, void* l) {
    __builtin_amdgcn_global_load_lds(
        (const __attribute__((address_space(1))) void*)g,
        (__attribute__((address_space(3))) void*)l, 16, 0, 0);
}

__device__ __forceinline__ void waitv(int allowed) {
    switch (allowed) {
        case 0: asm volatile("s_waitcnt vmcnt(0)" ::: "memory"); break;
        case 1: asm volatile("s_waitcnt vmcnt(1)" ::: "memory"); break;
        case 2: asm volatile("s_waitcnt vmcnt(2)" ::: "memory"); break;
        case 3: asm volatile("s_waitcnt vmcnt(3)" ::: "memory"); break;
        case 4: asm volatile("s_waitcnt vmcnt(4)" ::: "memory"); break;
        case 5: asm volatile("s_waitcnt vmcnt(5)" ::: "memory"); break;
        default: asm volatile("s_waitcnt vmcnt(0)" ::: "memory"); break;
    }
}

__device__ __forceinline__ float psroi_sample_f32(const float* __restrict__ plane,
                                                  float sw, float sh, float bw, float bh,
                                                  int ph, int pw)
{
    float acc = 0.0f;
    #pragma unroll
    for (int iy = 0; iy < SR; ++iy) {
        float y  = sh + ((float)ph + ((float)iy + 0.5f) * (1.0f / SR)) * bh;
        bool  vy = (y >= -1.0f) && (y <= (float)HH);
        float yy = fmaxf(y, 0.0f);
        int   y0 = min((int)floorf(yy), HH - 1);
        int   y1 = min(y0 + 1, HH - 1);
        float yc = (y0 >= HH - 1) ? (float)y0 : yy;
        float ly = yc - (float)y0;
        float hy = 1.0f - ly;
        #pragma unroll
        for (int ix = 0; ix < SR; ++ix) {
            float x  = sw + ((float)pw + ((float)ix + 0.5f) * (1.0f / SR)) * bw;
            bool  vx = (x >= -1.0f) && (x <= (float)WW);
            float xx = fmaxf(x, 0.0f);
            int   x0 = min((int)floorf(xx), WW - 1);
            int   x1 = min(x0 + 1, WW - 1);
            float xc = (x0 >= WW - 1) ? (float)x0 : xx;
            float lx = xc - (float)x0;
            float hx = 1.0f - lx;
            float v00 = plane[y0 * WW + x0];
            float v01 = plane[y0 * WW + x1];
            float v10 = plane[y1 * WW + x0];
            float v11 = plane[y1 * WW + x1];
            float v = hy * (hx * v00 + lx * v01) + ly * (hx * v10 + lx * v11);
            if (vy && vx) acc += v;
        }
    }
    return acc * (1.0f / (SR * SR));
}

// ---- kernel 1: one-time bucket ROIs by batch (aggregated global atomics) ----
__global__ __launch_bounds__(256) void build_lists_kernel(
    const float* __restrict__ rois, int N,
    int* __restrict__ counts, int* __restrict__ lists, float4* __restrict__ params)
{
    int tid  = blockIdx.x * blockDim.x + threadIdx.x;
    int lane = threadIdx.x & 63;
    int stride = gridDim.x * blockDim.x;
    for (int n = tid; n < N; n += stride) {
        const float* r = rois + (size_t)n * 5;
        int b = (int)r[0];
        float sw = r[1] * SCALE - 0.5f;
        float sh = r[2] * SCALE - 0.5f;
        float bw = (r[3] * SCALE - 0.5f - sw) * (1.0f / RS);
        float bh = (r[4] * SCALE - 0.5f - sh) * (1.0f / RS);
        int pos = 0;
        #pragma unroll
        for (int bb = 0; bb < NB; ++bb) {
            unsigned long long m = __ballot(b == bb);
            if (b == bb) {
                int rank = __popcll(m & ((1ull << lane) - 1ull));
                int base = 0;
                if (rank == 0) base = atomicAdd(&counts[bb], (int)__popcll(m));
                int leader = __ffsll((long long)m) - 1;
                base = __shfl(base, leader);
                pos = base + rank;
            }
        }
        lists[b * N + pos]  = n;
        params[b * N + pos] = make_float4(sw, sh, bw, bh);
    }
}

// ---- kernel 2: persistent 3-buffer pipeline (R13 structure, no scan, reg params) ----
__global__ __launch_bounds__(TPB) void psroi_pipe3_kernel(
    const float* __restrict__ feat, const int* __restrict__ counts,
    const int* __restrict__ lists, const float4* __restrict__ params,
    float* __restrict__ out, int N)
{
    __shared__ __align__(16) float buf0[BUFF];    // 40.96 KB each
    __shared__ __align__(16) float buf1[BUFF];
    __shared__ __align__(16) float buf2[BUFF];

    int tid  = threadIdx.x;
    int wid  = tid >> 6;
    int lane = tid & 63;
    int bid  = blockIdx.x;
    int xcd  = bid & 7;                 // heuristic XCD id (perf-only)
    int j    = bid >> 3;                // 0..31
    int b    = xcd >> 1;                // batch per slice-pair
    int cin0 = (xcd & 1) * 245 + j;     // tiles: cin0 + k*32
    int ntile = (244 - j) / 32 + 1;     // 7 or 8

    int cnt = counts[b];

    // ---- 1) load my ROI params into REGISTERS (one coalesced round) ----
    float psw[RSL], psh[RSL], pbw[RSL], pbh[RSL];
    int   pn[RSL];
    #pragma unroll
    for (int s = 0; s < RSL; ++s) {
        int i = tid + s * TPB;
        pn[s] = -1;
        psw[s] = psh[s] = pbw[s] = pbh[s] = 0.0f;
        if (i < cnt) {
            float4 p = params[b * N + i];
            pn[s] = lists[b * N + i];
            psw[s] = p.x; psh[s] = p.y; pbw[s] = p.z; pbh[s] = p.w;
        }
    }
    __builtin_amdgcn_sched_barrier(0);   // param loads issued before any gll

    // wave-uniform store count per tile (any-lane-active per slot)
    int wave_first = tid & ~63;
    int trips = 0;
    #pragma unroll
    for (int s = 0; s < RSL; ++s) if (wave_first + s * TPB < cnt) ++trips;

    // ---- 2) stage: 3 glls per wave (rounds 0,1 full; round 2 wave-pair dup) ----
    auto stage = [&](float* dst, int cin) {
        const char* gs = (const char*)(feat + (size_t)(b * CH + cin) * NPLANE);
        char* ls = (char*)dst;
        int wb = wid << 6;
        gll16(gs + (size_t)(tid) * 16,       ls + (size_t)(wb) * 16);
        gll16(gs + (size_t)(TPB + tid) * 16, ls + (size_t)(TPB + wb) * 16);
        int s2b = 2048 + ((wid & 7) << 6);            // waves w, w+8 duplicate
        int g2  = min(s2b + lane, 2499);              // clamp: pad gets finite junk
        gll16(gs + (size_t)g2 * 16,          ls + (size_t)s2b * 16);
    };

    stage(buf0, cin0);
    if (ntile > 1) stage(buf1, cin0 + 32);
    waitv(ntile > 1 ? 3 : 0);            // params + stage(t0) retired; t1 in flight
    __builtin_amdgcn_s_barrier();
    __builtin_amdgcn_sched_barrier(0);

    // ---- 3) pipelined tile loop ----
    for (int k = 0; k < ntile; ++k) {
        const float* __restrict__ bc = (k % 3 == 0) ? buf0 : ((k % 3 == 1) ? buf1 : buf2);
        if (k + 2 < ntile) {
            float* bn = ((k + 2) % 3 == 0) ? buf0 : (((k + 2) % 3 == 1) ? buf1 : buf2);
            stage(bn, cin0 + (k + 2) * 32);
        }
        __builtin_amdgcn_sched_barrier(0);

        int cin = cin0 + k * 32;
        int pw  = cin % RS;
        int ph  = (cin / RS) % RS;

        #pragma unroll
        for (int s = 0; s < RSL; ++s) {
            if (pn[s] >= 0) {
                float sw = psw[s], sh = psh[s], bw = pbw[s], bh = pbh[s];
                float acc = 0.0f;
                #pragma unroll
                for (int iy = 0; iy < SR; ++iy) {
                    float y  = sh + ((float)ph + ((float)iy + 0.5f) * (1.0f / SR)) * bh;
                    bool  vy = (y >= -1.0f) && (y <= (float)HH);
                    float yy = fmaxf(y, 0.0f);
                    int   y0 = min((int)floorf(yy), HH - 1);
                    float yc = (y0 >= HH - 1) ? (float)y0 : yy;
                    float ly = yc - (float)y0;
                    float hy = 1.0f - ly;
                    #pragma unroll
                    for (int ix = 0; ix < SR; ++ix) {
                        float x  = sw + ((float)pw + ((float)ix + 0.5f) * (1.0f / SR)) * bw;
                        bool  vx = (x >= -1.0f) && (x <= (float)WW);
                        float xx = fmaxf(x, 0.0f);
                        int   x0 = min((int)floorf(xx), WW - 1);
                        float xc = (x0 >= WW - 1) ? (float)x0 : xx;
                        float lx = xc - (float)x0;
                        float hx = 1.0f - lx;
                        // clamp-by-weight: stray taps (pad/junk) carry weight 0
                        int o = y0 * WW + x0;
                        float v00 = bc[o],      v01 = bc[o + 1];
                        float v10 = bc[o + WW], v11 = bc[o + WW + 1];
                        float v = hy * (hx * v00 + lx * v01) + ly * (hx * v10 + lx * v11);
                        if (vy && vx) acc += v;
                    }
                }
                out[(size_t)pn[s] * CH + cin] = acc * (1.0f / (SR * SR));
            }
        }

        if (k + 1 < ntile) {
            // wait own stage(k+1) glls retired; allow stage(k+2) glls + own stores
            waitv(trips + ((k + 2 < ntile) ? 3 : 0));
            __builtin_amdgcn_s_barrier();
            __builtin_amdgcn_sched_barrier(0);
        }
    }

    // ---- pathological overflow (cnt > RSL*TPB): direct-gather, never hit here ----
    if (cnt > RSL * TPB) {
        for (int k = 0; k < ntile; ++k) {
            int cin = cin0 + k * 32;
            int pw = cin % RS, ph = (cin / RS) % RS;
            const float* base = feat + (size_t)(b * CH + cin) * NPLANE;
            for (int i = RSL * TPB + tid; i < cnt; i += TPB) {
                float4 p = params[b * N + i];
                int n = lists[b * N + i];
                out[(size_t)n * CH + cin] =
                    psroi_sample_f32(base, p.x, p.y, p.z, p.w, ph, pw);
            }
        }
    }
}

// ---- general fallback (any B / N > MAXN / small ws): direct-gather ----
__global__ __launch_bounds__(256) void psroi_naive_kernel(
    const float* __restrict__ feat, const float* __restrict__ rois,
    float* __restrict__ out, int total)
{
    int o = blockIdx.x * blockDim.x + threadIdx.x;
    if (o >= total) return;
    int cin = o % CH;
    int n   = o / CH;
    int pw  = cin % RS;
    int ph  = (cin / RS) % RS;
    const float* r = rois + (size_t)n * 5;
    int bidx = (int)r[0];
    float sw = r[1] * SCALE - 0.5f;
    float sh = r[2] * SCALE - 0.5f;
    float bw = (r[3] * SCALE - 0.5f - sw) * (1.0f / RS);
    float bh = (r[4] * SCALE - 0.5f - sh) * (1.0f / RS);
    const float* base = feat + (size_t)(bidx * CH + cin) * NPLANE;
    out[o] = psroi_sample_f32(base, sw, sh, bw, bh, ph, pw);
}

extern "C" void kernel_launch(void* const* d_in, const int* in_sizes, int n_in,
                              void* d_out, int out_size, void* d_ws, size_t ws_size,
                              hipStream_t stream) {
    const float* feat = (const float*)d_in[0];
    const float* rois = (const float*)d_in[1];
    float* out = (float*)d_out;
    int N = in_sizes[1] / 5;
    int B = in_sizes[0] / (CH * NPLANE);

    size_t off_counts = 0;
    size_t off_lists  = 256;
    size_t off_params = (off_lists + (size_t)NB * N * sizeof(int) + 255) & ~(size_t)255;
    size_t need = off_params + (size_t)NB * N * sizeof(float4);

    if (N <= MAXN && B == 4 && ws_size >= need) {
        int*    counts = (int*)((char*)d_ws + off_counts);
        int*    lists  = (int*)((char*)d_ws + off_lists);
        float4* params = (float4*)((char*)d_ws + off_params);
        hipMemsetAsync(counts, 0, NB * sizeof(int), stream);
        build_lists_kernel<<<16, 256, 0, stream>>>(rois, N, counts, lists, params);
        psroi_pipe3_kernel<<<NBLK, TPB, 0, stream>>>(feat, counts, lists, params, out, N);
    } else {
        int total = N * CH;
        psroi_naive_kernel<<<(total + 255) / 256, 256, 0, stream>>>(feat, rois, out, total);
    }
}

// Round 17
// 28.092 us; speedup vs baseline: 1.2250x; 1.2250x over previous
//
#include <hip/hip_runtime.h>

#define RS 7
#define SR 2
#define PD 10
#define CH (PD * RS * RS)   // 490
#define SCALE (1.0f / 16.0f)
#define HH 100
#define WW 100
#define NPLANE (HH * WW)    // 10000
#define SLOTS 2556          // 16B slots per buffer (data 2500 + pad; tap idx <= 10100)
#define BUFN (SLOTS * 4)    // 10224 floats = 40896 B; 2 bufs = 81792 B -> 2 blocks/CU
#define TPB 512
#define NBLK 512            // 2 per CU
#define NB 4
#define MAXN 4096
#define RSL 3               // register param slots (covers cnt <= 1536)

// async global->LDS, 16B per lane; LDS dest is WAVE-UNIFORM base (+lane*16 by HW)
__device__ __forceinline__ void gll16(const void* g, void* l) {
    __builtin_amdgcn_global_load_lds(
        (const __attribute__((address_space(1))) void*)g,
        (__attribute__((address_space(3))) void*)l, 16, 0, 0);
}

__device__ __forceinline__ void waitv(int allowed) {
    switch (allowed) {
        case 0: asm volatile("s_waitcnt vmcnt(0)" ::: "memory"); break;
        case 1: asm volatile("s_waitcnt vmcnt(1)" ::: "memory"); break;
        case 2: asm volatile("s_waitcnt vmcnt(2)" ::: "memory"); break;
        case 3: asm volatile("s_waitcnt vmcnt(3)" ::: "memory"); break;
        default: asm volatile("s_waitcnt vmcnt(0)" ::: "memory"); break;
    }
}

__device__ __forceinline__ float psroi_sample_f32(const float* __restrict__ plane,
                                                  float sw, float sh, float bw, float bh,
                                                  int ph, int pw)
{
    float acc = 0.0f;
    #pragma unroll
    for (int iy = 0; iy < SR; ++iy) {
        float y  = sh + ((float)ph + ((float)iy + 0.5f) * (1.0f / SR)) * bh;
        bool  vy = (y >= -1.0f) && (y <= (float)HH);
        float yy = fmaxf(y, 0.0f);
        int   y0 = min((int)floorf(yy), HH - 1);
        int   y1 = min(y0 + 1, HH - 1);
        float yc = (y0 >= HH - 1) ? (float)y0 : yy;
        float ly = yc - (float)y0;
        float hy = 1.0f - ly;
        #pragma unroll
        for (int ix = 0; ix < SR; ++ix) {
            float x  = sw + ((float)pw + ((float)ix + 0.5f) * (1.0f / SR)) * bw;
            bool  vx = (x >= -1.0f) && (x <= (float)WW);
            float xx = fmaxf(x, 0.0f);
            int   x0 = min((int)floorf(xx), WW - 1);
            int   x1 = min(x0 + 1, WW - 1);
            float xc = (x0 >= WW - 1) ? (float)x0 : xx;
            float lx = xc - (float)x0;
            float hx = 1.0f - lx;
            float v00 = plane[y0 * WW + x0];
            float v01 = plane[y0 * WW + x1];
            float v10 = plane[y1 * WW + x0];
            float v11 = plane[y1 * WW + x1];
            float v = hy * (hx * v00 + lx * v01) + ly * (hx * v10 + lx * v11);
            if (vy && vx) acc += v;
        }
    }
    return acc * (1.0f / (SR * SR));
}

// persistent dbuf pipeline: 512 blocks (2/CU) x 512 thr, 3-4 tiles/block.
// In-kernel latency-flat scan; ROI params in registers; planes DMA'd to LDS.
__global__ __launch_bounds__(TPB, 2) void psroi_pipe2cu_kernel(
    const float* __restrict__ feat, const float* __restrict__ rois,
    float* __restrict__ out, int N)
{
    __shared__ __align__(16) float buf0[BUFN];    // 40896 B
    __shared__ __align__(16) float buf1[BUFN];    // 40896 B
    __shared__ int lcnt;

    int tid  = threadIdx.x;
    int wid  = tid >> 6;
    int lane = tid & 63;
    int bid  = blockIdx.x;
    int xcd  = bid & 7;                 // heuristic XCD id (perf-only)
    int i    = bid >> 3;                // 0..63 within XCD
    int b    = xcd >> 1;                // batch per half-slice pair
    int cin0 = (xcd & 1) * 245 + i;     // tiles: cin0 + k*64
    int nt   = (i <= 52) ? 4 : 3;       // 245 = 3*64 + 53

    if (tid == 0) lcnt = 0;
    __syncthreads();

    // ---- 1) latency-flat scan: prefetch all batch-ids, then compact ----
    float bf[8];
    #pragma unroll
    for (int s = 0; s < 8; ++s) {
        int k = s * TPB + tid;
        bf[s] = (k < N) ? rois[(size_t)k * 5] : -1.0f;
    }
    int* list = (int*)buf0;             // temp list in buf0
    #pragma unroll
    for (int s = 0; s < 8; ++s) {
        int k = s * TPB + tid;
        bool m = (k < N) && ((int)bf[s] == b);
        unsigned long long msk = __ballot(m);
        if (m) {
            int rank   = __popcll(msk & ((1ull << lane) - 1ull));
            int leader = __ffsll((long long)msk) - 1;
            int pos = 0;
            if (lane == leader) pos = atomicAdd(&lcnt, (int)__popcll(msk));
            pos = __shfl(pos, leader) + rank;
            list[pos] = k;
        }
    }
    __syncthreads();
    int cnt = lcnt;

    // ---- 2) my ROI params -> registers ----
    float psw[RSL], psh[RSL], pbw[RSL], pbh[RSL];
    int   pn[RSL];
    #pragma unroll
    for (int s = 0; s < RSL; ++s) {
        int ii = tid + s * TPB;
        pn[s] = -1;
        psw[s] = psh[s] = pbw[s] = pbh[s] = 0.0f;
        if (ii < cnt) {
            int n = list[ii];
            pn[s] = n;
            const float* rp = rois + (size_t)n * 5;
            float sw = rp[1] * SCALE - 0.5f;
            float sh = rp[2] * SCALE - 0.5f;
            psw[s] = sw;
            psh[s] = sh;
            pbw[s] = (rp[3] * SCALE - 0.5f - sw) * (1.0f / RS);
            pbh[s] = (rp[4] * SCALE - 0.5f - sh) * (1.0f / RS);
        }
    }

    // wave-uniform store-inst count per tile
    int wave_first = tid & ~63;
    int trips = 0;
    #pragma unroll
    for (int s = 0; s < RSL; ++s) if (wave_first + s * TPB < cnt) ++trips;

    // ---- 3) stage: exactly 5 glls per wave (last wave's tail window shifted) ----
    auto stage = [&](float* dst, int cin) {
        const char* gs = (const char*)(feat + (size_t)(b * CH + cin) * NPLANE);
        char* ls = (char*)dst;
        int wb = wid << 6;
        #pragma unroll
        for (int r = 0; r < 4; ++r)
            gll16(gs + (size_t)(r * TPB + tid) * 16, ls + (size_t)(r * TPB + wb) * 16);
        int base4 = min(2048 + wb, SLOTS - 64);      // wave7 shifts down 4 (dup data)
        int g4 = min(base4 + lane, 2499);            // clamp: pad slots get junk
        gll16(gs + (size_t)g4 * 16, ls + (size_t)base4 * 16);
    };

    stage(buf1, cin0);                  // tile0 -> buf1 (list in buf0 stays valid)
    __syncthreads();                    // drains params loads + stage(t0)

    // ---- 4) pipelined tile loop (double buffer) ----
    for (int k = 0; k < nt; ++k) {
        const float* __restrict__ bc = (k & 1) ? buf0 : buf1;
        if (k + 1 < nt) stage((k & 1) ? buf1 : buf0, cin0 + (k + 1) * 64);
        __builtin_amdgcn_sched_barrier(0);

        int cin = cin0 + k * 64;
        int pw  = cin % RS;
        int ph  = (cin / RS) % RS;

        #pragma unroll
        for (int s = 0; s < RSL; ++s) {
            if (pn[s] >= 0) {
                float sw = psw[s], sh = psh[s], bw = pbw[s], bh = pbh[s];
                float acc = 0.0f;
                #pragma unroll
                for (int iy = 0; iy < SR; ++iy) {
                    float y  = sh + ((float)ph + ((float)iy + 0.5f) * (1.0f / SR)) * bh;
                    bool  vy = (y >= -1.0f) && (y <= (float)HH);
                    float yy = fmaxf(y, 0.0f);
                    int   y0 = min((int)floorf(yy), HH - 1);
                    float yc = (y0 >= HH - 1) ? (float)y0 : yy;
                    float ly = yc - (float)y0;
                    float hy = 1.0f - ly;
                    #pragma unroll
                    for (int ix = 0; ix < SR; ++ix) {
                        float x  = sw + ((float)pw + ((float)ix + 0.5f) * (1.0f / SR)) * bw;
                        bool  vx = (x >= -1.0f) && (x <= (float)WW);
                        float xx = fmaxf(x, 0.0f);
                        int   x0 = min((int)floorf(xx), WW - 1);
                        float xc = (x0 >= WW - 1) ? (float)x0 : xx;
                        float lx = xc - (float)x0;
                        float hx = 1.0f - lx;
                        // clamp-by-weight: stray taps (pad/junk) carry weight 0
                        int o = y0 * WW + x0;
                        float v00 = bc[o],      v01 = bc[o + 1];
                        float v10 = bc[o + WW], v11 = bc[o + WW + 1];
                        float v = hy * (hx * v00 + lx * v01) + ly * (hx * v10 + lx * v11);
                        if (vy && vx) acc += v;
                    }
                }
                out[(size_t)pn[s] * CH + cin] = acc * (1.0f / (SR * SR));
            }
        }

        if (k + 1 < nt) {
            waitv(trips);               // stage(k+1) retired; own stores may linger
            __builtin_amdgcn_s_barrier();
            __builtin_amdgcn_sched_barrier(0);
        }
    }

    // ---- pathological overflow (cnt > RSL*TPB): direct global gather ----
    if (cnt > RSL * TPB) {
        for (int k = 0; k < nt; ++k) {
            int cin = cin0 + k * 64;
            int pw = cin % RS, ph = (cin / RS) % RS;
            const float* base = feat + (size_t)(b * CH + cin) * NPLANE;
            for (int ii = RSL * TPB + tid; ii < cnt; ii += TPB) {
                int n = ((int*)buf0)[0];  // list destroyed; rescan serially instead
                (void)n;
            }
            // rescan rois directly (rare; correctness-only path)
            for (int n = tid; n < N; n += TPB) {
                const float* rp = rois + (size_t)n * 5;
                if ((int)rp[0] != b) continue;
                // position in list unknown; recompute assignment: count preceding
                // matches is expensive -- instead just recompute ALL outputs for
                // this (b,cin) pair (idempotent, deterministic values)
                float sw = rp[1] * SCALE - 0.5f;
                float sh = rp[2] * SCALE - 0.5f;
                float bw = (rp[3] * SCALE - 0.5f - sw) * (1.0f / RS);
                float bh = (rp[4] * SCALE - 0.5f - sh) * (1.0f / RS);
                out[(size_t)n * CH + cin] =
                    psroi_sample_f32(base, sw, sh, bw, bh, ph, pw);
            }
        }
    }
}

// ---- general fallback (any B / N > MAXN): direct-gather per output ----
__global__ __launch_bounds__(256) void psroi_naive_kernel(
    const float* __restrict__ feat, const float* __restrict__ rois,
    float* __restrict__ out, int total)
{
    int o = blockIdx.x * blockDim.x + threadIdx.x;
    if (o >= total) return;
    int cin = o % CH;
    int n   = o / CH;
    int pw  = cin % RS;
    int ph  = (cin / RS) % RS;
    const float* r = rois + (size_t)n * 5;
    int bidx = (int)r[0];
    float sw = r[1] * SCALE - 0.5f;
    float sh = r[2] * SCALE - 0.5f;
    float bw = (r[3] * SCALE - 0.5f - sw) * (1.0f / RS);
    float bh = (r[4] * SCALE - 0.5f - sh) * (1.0f / RS);
    const float* base = feat + (size_t)(bidx * CH + cin) * NPLANE;
    out[o] = psroi_sample_f32(base, sw, sh, bw, bh, ph, pw);
}

extern "C" void kernel_launch(void* const* d_in, const int* in_sizes, int n_in,
                              void* d_out, int out_size, void* d_ws, size_t ws_size,
                              hipStream_t stream) {
    const float* feat = (const float*)d_in[0];
    const float* rois = (const float*)d_in[1];
    float* out = (float*)d_out;
    int N = in_sizes[1] / 5;
    int B = in_sizes[0] / (CH * NPLANE);

    if (N <= MAXN && B == 4) {
        psroi_pipe2cu_kernel<<<NBLK, TPB, 0, stream>>>(feat, rois, out, N);
    } else {
        int total = N * CH;
        psroi_naive_kernel<<<(total + 255) / 256, 256, 0, stream>>>(feat, rois, out, total);
    }
}